// Round 26
// baseline (142.233 us; speedup 1.0000x reference)
//
#include <hip/hip_runtime.h>
#include <hip/hip_bf16.h>

// Problem constants
#define B_   256
#define L_   197
#define C_   768
#define H_   48
#define NA_  10
#define ROWS (B_ * L_)            // 50432
#define TR   16                   // K3 tile rows; 50432 = 16*3152 exactly
#define XP   776                  // xs pitch (bf16): 768+8
#define HP   72                   // hs pitch (bf16): 64+8
#define NBLK (ROWS / TR)          // 3152
#define OFF_SIM 38731776          // B*L*C
#define OFF_IDX 38731777

typedef __attribute__((ext_vector_type(8))) short short8;
typedef __attribute__((ext_vector_type(4))) short short4_t;
typedef __attribute__((ext_vector_type(4))) float f32x4;

static __device__ inline short f2bf(float f) {
    union { float f; unsigned u; } v; v.f = f;
    unsigned r = v.u + 0x7fffu + ((v.u >> 16) & 1u);   // round-to-nearest-even
    return (short)(r >> 16);
}
static __device__ inline short bfc(float f) {
    __hip_bfloat16 h = __float2bfloat16(f);
    union { __hip_bfloat16 h; short s; } u; u.h = h;
    return u.s;
}
static __device__ inline float bf2f(short s) {
    union { unsigned u; float f; } v;
    v.u = ((unsigned)(unsigned short)s) << 16;
    return v.f;
}

#define GLW(dst, p, OFF) asm volatile("global_load_dwordx4 %0, %1, off offset:" OFF \
    : "=v"(dst) : "v"(p))

// ---------------------------------------------------------------------------
// KWA: merged k1a + kw_convert + zero of counts/done.
// grid = B*4 blocks of 256 threads.
// ---------------------------------------------------------------------------
__global__ void kwa_fused(const float* __restrict__ x, float* __restrict__ partial,
                          const float* __restrict__ W1, const float* __restrict__ W2,
                          short* __restrict__ W1b, short* __restrict__ W2b,
                          int* __restrict__ cnts) {
    int gid = blockIdx.x * 256 + threadIdx.x;  // 0..262143
    if (gid < NA_ + 1) cnts[gid] = 0;          // counts[10] + done
    for (int i = gid; i < NA_ * H_ * C_; i += B_ * 4 * 256)   // 368640
        W1b[i] = f2bf(W1[i]);
    for (int i = gid; i < NA_ * C_ * 64; i += B_ * 4 * 256) { // 491520
        int k  = i & 63;
        int nc = i >> 6;
        W2b[i] = (k < H_) ? f2bf(W2[nc * H_ + k]) : (short)0;
    }
    int t = threadIdx.x;
    if (t < 192) {
        int b = blockIdx.x >> 2, seg = blockIdx.x & 3;
        int l0 = seg * 50, l1 = l0 + 50; if (l1 > L_) l1 = L_;
        const float* xb = x + (size_t)b * L_ * C_ + t * 4;
        float4 s = {0.f, 0.f, 0.f, 0.f};
        #pragma unroll 5
        for (int l = l0; l < l1; ++l) {
            float4 v = *(const float4*)(xb + (size_t)l * C_);
            s.x += v.x; s.y += v.y; s.z += v.z; s.w += v.w;
        }
        *(float4*)(partial + ((size_t)b * 4 + seg) * C_ + t * 4) = s;
    }
}

// ---------------------------------------------------------------------------
// K1BC: fused sims + selection. grid = B blocks of 256.
// Each block b: mean -> sims[b][*], per-sample argmax -> atomicAdd(counts),
// threadfence, atomicAdd(done). Last block: majority (ties->smallest),
// reduce_sim (one sample per thread), idx + reduce_sim writes.
// ---------------------------------------------------------------------------
__global__ void k1bc_fused(const float* __restrict__ partial, const float* __restrict__ akey,
                           float* __restrict__ sims, int* __restrict__ cnts,
                           float* __restrict__ out, int* __restrict__ majorp) {
    __shared__ float red[21][256];
    __shared__ int lastS;
    __shared__ int mjS;
    __shared__ float rsum[256];
    int b = blockIdx.x, t = threadIdx.x;
    int* counts = cnts;
    int* done   = cnts + NA_;

    const float* p = partial + (size_t)b * 4 * C_;
    float m[3];
    #pragma unroll
    for (int j = 0; j < 3; ++j) {
        int c = t + j * 256;
        m[j] = (p[c] + p[C_ + c] + p[2 * C_ + c] + p[3 * C_ + c]) * (1.f / (float)L_);
    }
    red[0][t] = m[0] * m[0] + m[1] * m[1] + m[2] * m[2];
    #pragma unroll
    for (int k = 0; k < NA_; ++k) {
        float kd = 0.f, kq = 0.f;
        #pragma unroll
        for (int j = 0; j < 3; ++j) {
            float kv = akey[k * C_ + t + j * 256];
            kd += m[j] * kv; kq += kv * kv;
        }
        red[1 + k][t] = kd; red[11 + k][t] = kq;
    }
    __syncthreads();
    for (int s = 128; s > 0; s >>= 1) {
        if (t < s) {
            #pragma unroll
            for (int q = 0; q < 21; ++q) red[q][t] += red[q][t + s];
        }
        __syncthreads();
    }
    float rsm = rsqrtf(fmaxf(red[0][0], 1e-12f));
    if (t < NA_)
        sims[b * NA_ + t] = red[1 + t][0] * rsqrtf(fmaxf(red[11 + t][0], 1e-12f)) * rsm;
    __threadfence();
    __syncthreads();
    if (t == 0) {
        int best = 0;
        float bv = red[1][0] * rsqrtf(fmaxf(red[11][0], 1e-12f)) * rsm;
        #pragma unroll
        for (int k = 1; k < NA_; ++k) {
            float s = red[1 + k][0] * rsqrtf(fmaxf(red[11 + k][0], 1e-12f)) * rsm;
            if (s > bv) { bv = s; best = k; }
        }
        atomicAdd(&counts[best], 1);
        __threadfence();
        int my = atomicAdd(done, 1);
        lastS = (my == B_ - 1) ? 1 : 0;
    }
    __syncthreads();
    if (!lastS) return;
    __threadfence();
    if (t == 0) {
        int mj = 0, mc = counts[0];
        #pragma unroll
        for (int k = 1; k < NA_; ++k) { if (counts[k] > mc) { mc = counts[k]; mj = k; } }
        mjS = mj; *majorp = mj;
    }
    __syncthreads();
    int mj = mjS;
    rsum[t] = sims[t * NA_ + mj];
    __syncthreads();
    for (int st = 128; st > 0; st >>= 1) { if (t < st) rsum[t] += rsum[t + st]; __syncthreads(); }
    if (t == 0) out[OFF_SIM] = rsum[0] * (1.f / (float)B_);
    out[OFF_IDX + t] = (float)mj;
}

// ---------------------------------------------------------------------------
// K3: fused adapter apply (proven R24/R25 source, unchanged).
// ---------------------------------------------------------------------------
__launch_bounds__(192, 2)
__global__ void k3_apply(const float* __restrict__ x, const short* __restrict__ W1b,
                         const short* __restrict__ W2b, const int* __restrict__ majorp,
                         float* __restrict__ out) {
    __shared__ short xs[TR * XP];              // 24,832 B
    __shared__ short hs[TR * HP];              //  2,304 B
    const int major = *majorp;

    int t = threadIdx.x;                       // 0..191
    int w = t >> 6, l = t & 63;
    int rbase = blockIdx.x * TR;
    int lo16 = l & 15;
    int g = l >> 4;                            // 0..3
    int klane = g * 8;

    // ---- 1) stage x tile f32 -> bf16 LDS, forced-asm burst ----
    {
        const float* xsrc = x + (size_t)rbase * C_ + t * 4;
        const float* b0 = xsrc;
        const float* b1 = xsrc + 2 * C_;
        const float* b2 = xsrc + 4 * C_;
        const float* b3 = xsrc + 6 * C_;
        const float* b4 = xsrc + 8 * C_;
        const float* b5 = xsrc + 10 * C_;
        const float* b6 = xsrc + 12 * C_;
        const float* b7 = xsrc + 14 * C_;
        f32x4 v0, v1, v2, v3, v4, v5, v6, v7, v8, v9, v10, v11, v12, v13, v14, v15;
        GLW(v0,  b0, "0"); GLW(v1,  b0, "3072");
        GLW(v2,  b1, "0"); GLW(v3,  b1, "3072");
        GLW(v4,  b2, "0"); GLW(v5,  b2, "3072");
        GLW(v6,  b3, "0"); GLW(v7,  b3, "3072");
        GLW(v8,  b4, "0"); GLW(v9,  b4, "3072");
        GLW(v10, b5, "0"); GLW(v11, b5, "3072");
        GLW(v12, b6, "0"); GLW(v13, b6, "3072");
        GLW(v14, b7, "0"); GLW(v15, b7, "3072");

#define STROW(ROW, V) { \
        short4_t sb; \
        sb[0] = bfc((V)[0]); sb[1] = bfc((V)[1]); \
        sb[2] = bfc((V)[2]); sb[3] = bfc((V)[3]); \
        *(short4_t*)&xs[(ROW) * XP + t * 4] = sb; }

        asm volatile("s_waitcnt vmcnt(8)"
            : "+v"(v0), "+v"(v1), "+v"(v2), "+v"(v3),
              "+v"(v4), "+v"(v5), "+v"(v6), "+v"(v7));
        __builtin_amdgcn_sched_barrier(0);
        STROW(0, v0) STROW(1, v1) STROW(2, v2) STROW(3, v3)
        STROW(4, v4) STROW(5, v5) STROW(6, v6) STROW(7, v7)
        asm volatile("s_waitcnt vmcnt(0)"
            : "+v"(v8), "+v"(v9), "+v"(v10), "+v"(v11),
              "+v"(v12), "+v"(v13), "+v"(v14), "+v"(v15));
        __builtin_amdgcn_sched_barrier(0);
        STROW(8, v8)   STROW(9, v9)   STROW(10, v10) STROW(11, v11)
        STROW(12, v12) STROW(13, v13) STROW(14, v14) STROW(15, v15)
#undef STROW
    }
    __syncthreads();

    // ---- 2) GEMM1: wave w computes n-tile w of h = relu(x @ W1^T) ----
    {
        const short* w1p = W1b + major * (H_ * C_) + (size_t)(w * 16 + lo16) * C_ + klane;
        f32x4 acc = {0, 0, 0, 0};
        short8 q0, q1, q2, q3, q4, q5, q6, q7, q8, q9, q10, q11;
        short8 q12, q13, q14, q15, q16, q17, q18, q19, q20, q21, q22, q23;

#define G1STEP(KK, Q) { \
        short8 xa = *(const short8*)&xs[lo16 * XP + (KK) * 32 + klane]; \
        acc = __builtin_amdgcn_mfma_f32_16x16x32_bf16(xa, Q, acc, 0, 0, 0); }

        GLW(q0,  w1p, "0");    GLW(q1,  w1p, "64");   GLW(q2,  w1p, "128");
        GLW(q3,  w1p, "192");  GLW(q4,  w1p, "256");  GLW(q5,  w1p, "320");
        GLW(q6,  w1p, "384");  GLW(q7,  w1p, "448");  GLW(q8,  w1p, "512");
        GLW(q9,  w1p, "576");  GLW(q10, w1p, "640");  GLW(q11, w1p, "704");
        GLW(q12, w1p, "768");  GLW(q13, w1p, "832");  GLW(q14, w1p, "896");
        GLW(q15, w1p, "960");  GLW(q16, w1p, "1024"); GLW(q17, w1p, "1088");
        GLW(q18, w1p, "1152"); GLW(q19, w1p, "1216"); GLW(q20, w1p, "1280");
        GLW(q21, w1p, "1344"); GLW(q22, w1p, "1408"); GLW(q23, w1p, "1472");
        asm volatile("s_waitcnt vmcnt(12)"
            : "+v"(q0), "+v"(q1), "+v"(q2), "+v"(q3), "+v"(q4), "+v"(q5),
              "+v"(q6), "+v"(q7), "+v"(q8), "+v"(q9), "+v"(q10), "+v"(q11));
        __builtin_amdgcn_sched_barrier(0);
        __builtin_amdgcn_s_setprio(1);
        G1STEP(0, q0)  G1STEP(1, q1)  G1STEP(2, q2)  G1STEP(3, q3)
        G1STEP(4, q4)  G1STEP(5, q5)  G1STEP(6, q6)  G1STEP(7, q7)
        G1STEP(8, q8)  G1STEP(9, q9)  G1STEP(10, q10) G1STEP(11, q11)
        __builtin_amdgcn_s_setprio(0);
        asm volatile("s_waitcnt vmcnt(0)"
            : "+v"(q12), "+v"(q13), "+v"(q14), "+v"(q15), "+v"(q16), "+v"(q17),
              "+v"(q18), "+v"(q19), "+v"(q20), "+v"(q21), "+v"(q22), "+v"(q23));
        __builtin_amdgcn_sched_barrier(0);
        __builtin_amdgcn_s_setprio(1);
        G1STEP(12, q12) G1STEP(13, q13) G1STEP(14, q14) G1STEP(15, q15)
        G1STEP(16, q16) G1STEP(17, q17) G1STEP(18, q18) G1STEP(19, q19)
        G1STEP(20, q20) G1STEP(21, q21) G1STEP(22, q22) G1STEP(23, q23)
        __builtin_amdgcn_s_setprio(0);
#undef G1STEP

        #pragma unroll
        for (int q = 0; q < 4; ++q)
            hs[(g * 4 + q) * HP + w * 16 + lo16] = bfc(fmaxf(acc[q], 0.f));
        if (w == 0) {
            short4_t z = {0, 0, 0, 0};
            *(short4_t*)&hs[lo16 * HP + 48 + g * 4] = z;
        }
    }
    __syncthreads();

    // ---- 3) GEMM2 + bias + DIRECT global store. Wave w: cols w*256..+255 ----
    {
        short8 hA = *(const short8*)&hs[lo16 * HP + klane];
        short8 hB = *(const short8*)&hs[lo16 * HP + 32 + klane];
        const short* ba = W2b + (size_t)major * (C_ * 64)
                              + (size_t)(w * 16) * 1024 + lo16 * 64 + klane;
        const short* b1 = ba + 2048;
        const short* b2 = ba + 4096;
        const short* b3 = ba + 6144;
        const short* b4 = ba + 8192;
        const short* b5 = ba + 10240;
        const short* b6 = ba + 12288;
        const short* b7 = ba + 14336;
        short8 p0a, p0b, p1a, p1b, p2a, p2b, p3a, p3b;
        short8 p4a, p4b, p5a, p5b, p6a, p6b, p7a, p7b;
        short8 p8a, p8b, p9a, p9b, p10a, p10b, p11a, p11b;
        short8 p12a, p12b, p13a, p13b, p14a, p14b, p15a, p15b;

        GLW(p0a,  ba, "0");    GLW(p0b,  ba, "64");
        GLW(p1a,  ba, "2048"); GLW(p1b,  ba, "2112");
        GLW(p2a,  b1, "0");    GLW(p2b,  b1, "64");
        GLW(p3a,  b1, "2048"); GLW(p3b,  b1, "2112");
        GLW(p4a,  b2, "0");    GLW(p4b,  b2, "64");
        GLW(p5a,  b2, "2048"); GLW(p5b,  b2, "2112");
        GLW(p6a,  b3, "0");    GLW(p6b,  b3, "64");
        GLW(p7a,  b3, "2048"); GLW(p7b,  b3, "2112");
        GLW(p8a,  b4, "0");    GLW(p8b,  b4, "64");
        GLW(p9a,  b4, "2048"); GLW(p9b,  b4, "2112");
        GLW(p10a, b5, "0");    GLW(p10b, b5, "64");
        GLW(p11a, b5, "2048"); GLW(p11b, b5, "2112");
        GLW(p12a, b6, "0");    GLW(p12b, b6, "64");
        GLW(p13a, b6, "2048"); GLW(p13b, b6, "2112");
        GLW(p14a, b7, "0");    GLW(p14b, b7, "64");
        GLW(p15a, b7, "2048"); GLW(p15b, b7, "2112");

        float* outr = out + (size_t)(rbase + lo16) * C_ + w * 256 + g * 4;

#define G2STEP(JJ, P0, P1) { \
        f32x4 acc = {0, 0, 0, 0}; \
        acc = __builtin_amdgcn_mfma_f32_16x16x32_bf16(P0, hA, acc, 0, 0, 0); \
        acc = __builtin_amdgcn_mfma_f32_16x16x32_bf16(P1, hB, acc, 0, 0, 0); \
        short4_t xbv = *(const short4_t*)&xs[lo16 * XP + (w * 16 + (JJ)) * 16 + g * 4]; \
        f32x4 ov; \
        ov[0] = bf2f(xbv[0]) + fmaxf(acc[0], 0.f); \
        ov[1] = bf2f(xbv[1]) + fmaxf(acc[1], 0.f); \
        ov[2] = bf2f(xbv[2]) + fmaxf(acc[2], 0.f); \
        ov[3] = bf2f(xbv[3]) + fmaxf(acc[3], 0.f); \
        *(f32x4*)(outr + (JJ) * 16) = ov; }

        asm volatile("s_waitcnt vmcnt(16)"
            : "+v"(p0a), "+v"(p0b), "+v"(p1a), "+v"(p1b),
              "+v"(p2a), "+v"(p2b), "+v"(p3a), "+v"(p3b),
              "+v"(p4a), "+v"(p4b), "+v"(p5a), "+v"(p5b),
              "+v"(p6a), "+v"(p6b), "+v"(p7a), "+v"(p7b));
        __builtin_amdgcn_sched_barrier(0);
        __builtin_amdgcn_s_setprio(1);
        G2STEP(0, p0a, p0b)   G2STEP(1, p1a, p1b)
        G2STEP(2, p2a, p2b)   G2STEP(3, p3a, p3b)
        G2STEP(4, p4a, p4b)   G2STEP(5, p5a, p5b)
        G2STEP(6, p6a, p6b)   G2STEP(7, p7a, p7b)
        __builtin_amdgcn_s_setprio(0);
        asm volatile("s_waitcnt vmcnt(0)"
            : "+v"(p8a), "+v"(p8b), "+v"(p9a), "+v"(p9b),
              "+v"(p10a), "+v"(p10b), "+v"(p11a), "+v"(p11b),
              "+v"(p12a), "+v"(p12b), "+v"(p13a), "+v"(p13b),
              "+v"(p14a), "+v"(p14b), "+v"(p15a), "+v"(p15b));
        __builtin_amdgcn_sched_barrier(0);
        __builtin_amdgcn_s_setprio(1);
        G2STEP(8, p8a, p8b)   G2STEP(9, p9a, p9b)
        G2STEP(10, p10a, p10b) G2STEP(11, p11a, p11b)
        G2STEP(12, p12a, p12b) G2STEP(13, p13a, p13b)
        G2STEP(14, p14a, p14b) G2STEP(15, p15a, p15b)
        __builtin_amdgcn_s_setprio(0);
#undef G2STEP
    }
}

// ---------------------------------------------------------------------------
extern "C" void kernel_launch(void* const* d_in, const int* in_sizes, int n_in,
                              void* d_out, int out_size, void* d_ws, size_t ws_size,
                              hipStream_t stream) {
    const float* x    = (const float*)d_in[0];
    const float* W1   = (const float*)d_in[1];
    const float* W2   = (const float*)d_in[2];
    const float* akey = (const float*)d_in[3];
    float* out = (float*)d_out;

    char* ws = (char*)d_ws;
    short* W1b     = (short*)ws;                       //   737,280 B
    short* W2b     = (short*)(ws + 737280);            //   983,040 B
    float* partial = (float*)(ws + 1720320);           // 3,145,728 B
    float* sims    = (float*)(ws + 4866048);           //    10,240 B
    int*   majorp  = (int*)(ws + 4876288);             //         4 B
    int*   cnts    = (int*)(ws + 4876292);             //  11 ints: counts[10] + done

    hipLaunchKernelGGL(kwa_fused, dim3(B_ * 4), dim3(256), 0, stream,
                       x, partial, W1, W2, W1b, W2b, cnts);
    hipLaunchKernelGGL(k1bc_fused, dim3(B_), dim3(256), 0, stream,
                       partial, akey, sims, cnts, out, majorp);
    hipLaunchKernelGGL(k3_apply, dim3(NBLK), dim3(192), 0, stream, x, W1b, W2b, majorp, out);
}

// Round 27
// 123.011 us; speedup vs baseline: 1.1563x; 1.1563x over previous
//
#include <hip/hip_runtime.h>
#include <hip/hip_bf16.h>

// Problem constants
#define B_   256
#define L_   197
#define C_   768
#define H_   48
#define NA_  10
#define ROWS (B_ * L_)            // 50432
#define TR   16                   // K3 tile rows; 50432 = 16*3152 exactly
#define XP   776                  // xs pitch (bf16): 768+8; row stride 1552B
#define HP   72                   // hs pitch (bf16): 64+8
#define NBLK (ROWS / TR)          // 3152
#define OFF_SIM 38731776          // B*L*C
#define OFF_IDX 38731777

typedef __attribute__((ext_vector_type(8))) short short8;
typedef __attribute__((ext_vector_type(4))) short short4_t;
typedef __attribute__((ext_vector_type(4))) float f32x4;

static __device__ inline short f2bf(float f) {
    union { float f; unsigned u; } v; v.f = f;
    unsigned r = v.u + 0x7fffu + ((v.u >> 16) & 1u);   // round-to-nearest-even
    return (short)(r >> 16);
}
// native RNE cvt -> compiler emits v_cvt_pk_bf16_f32 for pairs
static __device__ inline short bfc(float f) {
    __hip_bfloat16 h = __float2bfloat16(f);
    union { __hip_bfloat16 h; short s; } u; u.h = h;
    return u.s;
}
static __device__ inline float bf2f(short s) {
    union { unsigned u; float f; } v;
    v.u = ((unsigned)(unsigned short)s) << 16;
    return v.f;
}

#define GLW(dst, p, OFF) asm volatile("global_load_dwordx4 %0, %1, off offset:" OFF \
    : "=v"(dst) : "v"(p))

// ---------------------------------------------------------------------------
// KWA: merged k1a + kw_convert. grid = B*4 blocks of 256 threads.
// Threads 0..191: partial sums over L for (b, seg). All 256 threads: grid-
// stride conversion of W1 [10,48,768] and W2 (K-padded to 64) to bf16.
// ---------------------------------------------------------------------------
__global__ void kwa_fused(const float* __restrict__ x, float* __restrict__ partial,
                          const float* __restrict__ W1, const float* __restrict__ W2,
                          short* __restrict__ W1b, short* __restrict__ W2b) {
    int gid = blockIdx.x * 256 + threadIdx.x;  // 0..262143
    for (int i = gid; i < NA_ * H_ * C_; i += B_ * 4 * 256)   // 368640
        W1b[i] = f2bf(W1[i]);
    for (int i = gid; i < NA_ * C_ * 64; i += B_ * 4 * 256) { // 491520
        int k  = i & 63;
        int nc = i >> 6;                       // a*768 + c
        W2b[i] = (k < H_) ? f2bf(W2[nc * H_ + k]) : (short)0;
    }
    int t = threadIdx.x;
    if (t < 192) {
        int b = blockIdx.x >> 2, seg = blockIdx.x & 3;
        int l0 = seg * 50, l1 = l0 + 50; if (l1 > L_) l1 = L_;
        const float* xb = x + (size_t)b * L_ * C_ + t * 4;
        float4 s = {0.f, 0.f, 0.f, 0.f};
        #pragma unroll 5
        for (int l = l0; l < l1; ++l) {
            float4 v = *(const float4*)(xb + (size_t)l * C_);
            s.x += v.x; s.y += v.y; s.z += v.z; s.w += v.w;
        }
        *(float4*)(partial + ((size_t)b * 4 + seg) * C_ + t * 4) = s;
    }
}

// ---------------------------------------------------------------------------
// K1b: per-b mean -> sims[b][k]
// ---------------------------------------------------------------------------
__global__ void k1b_sims(const float* __restrict__ partial, const float* __restrict__ akey,
                         float* __restrict__ sims) {
    __shared__ float red[21][256];
    int b = blockIdx.x, t = threadIdx.x;
    const float* p = partial + (size_t)b * 4 * C_;
    float m[3];
    #pragma unroll
    for (int j = 0; j < 3; ++j) {
        int c = t + j * 256;
        m[j] = (p[c] + p[C_ + c] + p[2 * C_ + c] + p[3 * C_ + c]) * (1.f / (float)L_);
    }
    red[0][t] = m[0] * m[0] + m[1] * m[1] + m[2] * m[2];
    #pragma unroll
    for (int k = 0; k < NA_; ++k) {
        float kd = 0.f, kq = 0.f;
        #pragma unroll
        for (int j = 0; j < 3; ++j) {
            float kv = akey[k * C_ + t + j * 256];
            kd += m[j] * kv; kq += kv * kv;
        }
        red[1 + k][t] = kd; red[11 + k][t] = kq;
    }
    __syncthreads();
    for (int s = 128; s > 0; s >>= 1) {
        if (t < s) {
            #pragma unroll
            for (int q = 0; q < 21; ++q) red[q][t] += red[q][t + s];
        }
        __syncthreads();
    }
    if (t < NA_) {
        float msq = red[0][0];
        sims[b * NA_ + t] = red[1 + t][0] * rsqrtf(fmaxf(red[11 + t][0], 1e-12f))
                                          * rsqrtf(fmaxf(msq, 1e-12f));
    }
}

// ---------------------------------------------------------------------------
// K2: single block. argmax + majority vote + reduce_sim + idx
// ---------------------------------------------------------------------------
__global__ void k2_select(const float* __restrict__ sims, float* __restrict__ out,
                          int* __restrict__ majorp) {
    __shared__ int counts[NA_];
    __shared__ int majorS;
    __shared__ float rs[256];
    int t = threadIdx.x;                       // = b
    float s[NA_];
    #pragma unroll
    for (int k = 0; k < NA_; ++k) s[k] = sims[t * NA_ + k];
    int best = 0; float bv = s[0];
    #pragma unroll
    for (int k = 1; k < NA_; ++k) { if (s[k] > bv) { bv = s[k]; best = k; } }
    if (t < NA_) counts[t] = 0;
    __syncthreads();
    atomicAdd(&counts[best], 1);
    __syncthreads();
    if (t == 0) {
        int mj = 0, mc = counts[0];
        #pragma unroll
        for (int k = 1; k < NA_; ++k) { if (counts[k] > mc) { mc = counts[k]; mj = k; } }
        majorS = mj; *majorp = mj;
    }
    __syncthreads();
    int mj = majorS;
    rs[t] = s[mj];
    __syncthreads();
    for (int st = 128; st > 0; st >>= 1) { if (t < st) rs[t] += rs[t + st]; __syncthreads(); }
    if (t == 0) out[OFF_SIM] = rs[0] * (1.f / (float)B_);
    out[OFF_IDX + t] = (float)mj;
}

// ---------------------------------------------------------------------------
// K3: fused adapter apply (proven R24/R25 source, unchanged).
// grid = 3152 blocks x 192 threads (3 waves). LDS 27.1KB. Stage f32->bf16
// via forced-asm bursts; GEMM1 W1 deep burst vmcnt(12)/vmcnt(0); GEMM2 W2
// deep burst vmcnt(16)/vmcnt(0); bias from bf16 xs; direct f32x4 stores;
// setprio around MFMA clusters (neutral, harmless).
// ---------------------------------------------------------------------------
__launch_bounds__(192, 2)
__global__ void k3_apply(const float* __restrict__ x, const short* __restrict__ W1b,
                         const short* __restrict__ W2b, const int* __restrict__ majorp,
                         float* __restrict__ out) {
    __shared__ short xs[TR * XP];              // 24,832 B
    __shared__ short hs[TR * HP];              //  2,304 B
    const int major = *majorp;

    int t = threadIdx.x;                       // 0..191
    int w = t >> 6, l = t & 63;
    int rbase = blockIdx.x * TR;
    int lo16 = l & 15;
    int g = l >> 4;                            // 0..3
    int klane = g * 8;

    // ---- 1) stage x tile f32 -> bf16 LDS, forced-asm burst ----
    {
        const float* xsrc = x + (size_t)rbase * C_ + t * 4;
        const float* b0 = xsrc;                // rows 0,1
        const float* b1 = xsrc + 2 * C_;       // rows 2,3
        const float* b2 = xsrc + 4 * C_;
        const float* b3 = xsrc + 6 * C_;
        const float* b4 = xsrc + 8 * C_;
        const float* b5 = xsrc + 10 * C_;
        const float* b6 = xsrc + 12 * C_;
        const float* b7 = xsrc + 14 * C_;
        f32x4 v0, v1, v2, v3, v4, v5, v6, v7, v8, v9, v10, v11, v12, v13, v14, v15;
        GLW(v0,  b0, "0"); GLW(v1,  b0, "3072");
        GLW(v2,  b1, "0"); GLW(v3,  b1, "3072");
        GLW(v4,  b2, "0"); GLW(v5,  b2, "3072");
        GLW(v6,  b3, "0"); GLW(v7,  b3, "3072");
        GLW(v8,  b4, "0"); GLW(v9,  b4, "3072");
        GLW(v10, b5, "0"); GLW(v11, b5, "3072");
        GLW(v12, b6, "0"); GLW(v13, b6, "3072");
        GLW(v14, b7, "0"); GLW(v15, b7, "3072");

#define STROW(ROW, V) { \
        short4_t sb; \
        sb[0] = bfc((V)[0]); sb[1] = bfc((V)[1]); \
        sb[2] = bfc((V)[2]); sb[3] = bfc((V)[3]); \
        *(short4_t*)&xs[(ROW) * XP + t * 4] = sb; }

        asm volatile("s_waitcnt vmcnt(8)"
            : "+v"(v0), "+v"(v1), "+v"(v2), "+v"(v3),
              "+v"(v4), "+v"(v5), "+v"(v6), "+v"(v7));
        __builtin_amdgcn_sched_barrier(0);
        STROW(0, v0) STROW(1, v1) STROW(2, v2) STROW(3, v3)
        STROW(4, v4) STROW(5, v5) STROW(6, v6) STROW(7, v7)
        asm volatile("s_waitcnt vmcnt(0)"
            : "+v"(v8), "+v"(v9), "+v"(v10), "+v"(v11),
              "+v"(v12), "+v"(v13), "+v"(v14), "+v"(v15));
        __builtin_amdgcn_sched_barrier(0);
        STROW(8, v8)   STROW(9, v9)   STROW(10, v10) STROW(11, v11)
        STROW(12, v12) STROW(13, v13) STROW(14, v14) STROW(15, v15)
#undef STROW
    }
    __syncthreads();

    // ---- 2) GEMM1: wave w computes n-tile w of h = relu(x @ W1^T) ----
    {
        const short* w1p = W1b + major * (H_ * C_) + (size_t)(w * 16 + lo16) * C_ + klane;
        f32x4 acc = {0, 0, 0, 0};
        short8 q0, q1, q2, q3, q4, q5, q6, q7, q8, q9, q10, q11;
        short8 q12, q13, q14, q15, q16, q17, q18, q19, q20, q21, q22, q23;

#define G1STEP(KK, Q) { \
        short8 xa = *(const short8*)&xs[lo16 * XP + (KK) * 32 + klane]; \
        acc = __builtin_amdgcn_mfma_f32_16x16x32_bf16(xa, Q, acc, 0, 0, 0); }

        GLW(q0,  w1p, "0");    GLW(q1,  w1p, "64");   GLW(q2,  w1p, "128");
        GLW(q3,  w1p, "192");  GLW(q4,  w1p, "256");  GLW(q5,  w1p, "320");
        GLW(q6,  w1p, "384");  GLW(q7,  w1p, "448");  GLW(q8,  w1p, "512");
        GLW(q9,  w1p, "576");  GLW(q10, w1p, "640");  GLW(q11, w1p, "704");
        GLW(q12, w1p, "768");  GLW(q13, w1p, "832");  GLW(q14, w1p, "896");
        GLW(q15, w1p, "960");  GLW(q16, w1p, "1024"); GLW(q17, w1p, "1088");
        GLW(q18, w1p, "1152"); GLW(q19, w1p, "1216"); GLW(q20, w1p, "1280");
        GLW(q21, w1p, "1344"); GLW(q22, w1p, "1408"); GLW(q23, w1p, "1472");
        asm volatile("s_waitcnt vmcnt(12)"
            : "+v"(q0), "+v"(q1), "+v"(q2), "+v"(q3), "+v"(q4), "+v"(q5),
              "+v"(q6), "+v"(q7), "+v"(q8), "+v"(q9), "+v"(q10), "+v"(q11));
        __builtin_amdgcn_sched_barrier(0);
        __builtin_amdgcn_s_setprio(1);
        G1STEP(0, q0)  G1STEP(1, q1)  G1STEP(2, q2)  G1STEP(3, q3)
        G1STEP(4, q4)  G1STEP(5, q5)  G1STEP(6, q6)  G1STEP(7, q7)
        G1STEP(8, q8)  G1STEP(9, q9)  G1STEP(10, q10) G1STEP(11, q11)
        __builtin_amdgcn_s_setprio(0);
        asm volatile("s_waitcnt vmcnt(0)"
            : "+v"(q12), "+v"(q13), "+v"(q14), "+v"(q15), "+v"(q16), "+v"(q17),
              "+v"(q18), "+v"(q19), "+v"(q20), "+v"(q21), "+v"(q22), "+v"(q23));
        __builtin_amdgcn_sched_barrier(0);
        __builtin_amdgcn_s_setprio(1);
        G1STEP(12, q12) G1STEP(13, q13) G1STEP(14, q14) G1STEP(15, q15)
        G1STEP(16, q16) G1STEP(17, q17) G1STEP(18, q18) G1STEP(19, q19)
        G1STEP(20, q20) G1STEP(21, q21) G1STEP(22, q22) G1STEP(23, q23)
        __builtin_amdgcn_s_setprio(0);
#undef G1STEP

        // h -> hs (D: col n=lo16 (W1 row), row m=g*4+q (x row))
        #pragma unroll
        for (int q = 0; q < 4; ++q)
            hs[(g * 4 + q) * HP + w * 16 + lo16] = bfc(fmaxf(acc[q], 0.f));
        // K-pad zero [48,64): wave 0 covers 16 rows x 16 cols
        if (w == 0) {
            short4_t z = {0, 0, 0, 0};
            *(short4_t*)&hs[lo16 * HP + 48 + g * 4] = z;
        }
    }
    __syncthreads();

    // ---- 3) GEMM2 + bias + DIRECT global store. Wave w: cols w*256..+255 ----
    {
        short8 hA = *(const short8*)&hs[lo16 * HP + klane];
        short8 hB = *(const short8*)&hs[lo16 * HP + 32 + klane];
        const short* ba = W2b + (size_t)major * (C_ * 64)
                              + (size_t)(w * 16) * 1024 + lo16 * 64 + klane;
        const short* b1 = ba + 2048;
        const short* b2 = ba + 4096;
        const short* b3 = ba + 6144;
        const short* b4 = ba + 8192;
        const short* b5 = ba + 10240;
        const short* b6 = ba + 12288;
        const short* b7 = ba + 14336;
        short8 p0a, p0b, p1a, p1b, p2a, p2b, p3a, p3b;
        short8 p4a, p4b, p5a, p5b, p6a, p6b, p7a, p7b;
        short8 p8a, p8b, p9a, p9b, p10a, p10b, p11a, p11b;
        short8 p12a, p12b, p13a, p13b, p14a, p14b, p15a, p15b;

        GLW(p0a,  ba, "0");    GLW(p0b,  ba, "64");
        GLW(p1a,  ba, "2048"); GLW(p1b,  ba, "2112");
        GLW(p2a,  b1, "0");    GLW(p2b,  b1, "64");
        GLW(p3a,  b1, "2048"); GLW(p3b,  b1, "2112");
        GLW(p4a,  b2, "0");    GLW(p4b,  b2, "64");
        GLW(p5a,  b2, "2048"); GLW(p5b,  b2, "2112");
        GLW(p6a,  b3, "0");    GLW(p6b,  b3, "64");
        GLW(p7a,  b3, "2048"); GLW(p7b,  b3, "2112");
        GLW(p8a,  b4, "0");    GLW(p8b,  b4, "64");
        GLW(p9a,  b4, "2048"); GLW(p9b,  b4, "2112");
        GLW(p10a, b5, "0");    GLW(p10b, b5, "64");
        GLW(p11a, b5, "2048"); GLW(p11b, b5, "2112");
        GLW(p12a, b6, "0");    GLW(p12b, b6, "64");
        GLW(p13a, b6, "2048"); GLW(p13b, b6, "2112");
        GLW(p14a, b7, "0");    GLW(p14b, b7, "64");
        GLW(p15a, b7, "2048"); GLW(p15b, b7, "2112");

        float* outr = out + (size_t)(rbase + lo16) * C_ + w * 256 + g * 4;

#define G2STEP(JJ, P0, P1) { \
        f32x4 acc = {0, 0, 0, 0}; \
        acc = __builtin_amdgcn_mfma_f32_16x16x32_bf16(P0, hA, acc, 0, 0, 0); \
        acc = __builtin_amdgcn_mfma_f32_16x16x32_bf16(P1, hB, acc, 0, 0, 0); \
        short4_t xbv = *(const short4_t*)&xs[lo16 * XP + (w * 16 + (JJ)) * 16 + g * 4]; \
        f32x4 ov; \
        ov[0] = bf2f(xbv[0]) + fmaxf(acc[0], 0.f); \
        ov[1] = bf2f(xbv[1]) + fmaxf(acc[1], 0.f); \
        ov[2] = bf2f(xbv[2]) + fmaxf(acc[2], 0.f); \
        ov[3] = bf2f(xbv[3]) + fmaxf(acc[3], 0.f); \
        *(f32x4*)(outr + (JJ) * 16) = ov; }

        asm volatile("s_waitcnt vmcnt(16)"
            : "+v"(p0a), "+v"(p0b), "+v"(p1a), "+v"(p1b),
              "+v"(p2a), "+v"(p2b), "+v"(p3a), "+v"(p3b),
              "+v"(p4a), "+v"(p4b), "+v"(p5a), "+v"(p5b),
              "+v"(p6a), "+v"(p6b), "+v"(p7a), "+v"(p7b));
        __builtin_amdgcn_sched_barrier(0);
        __builtin_amdgcn_s_setprio(1);
        G2STEP(0, p0a, p0b)   G2STEP(1, p1a, p1b)
        G2STEP(2, p2a, p2b)   G2STEP(3, p3a, p3b)
        G2STEP(4, p4a, p4b)   G2STEP(5, p5a, p5b)
        G2STEP(6, p6a, p6b)   G2STEP(7, p7a, p7b)
        __builtin_amdgcn_s_setprio(0);
        asm volatile("s_waitcnt vmcnt(0)"
            : "+v"(p8a), "+v"(p8b), "+v"(p9a), "+v"(p9b),
              "+v"(p10a), "+v"(p10b), "+v"(p11a), "+v"(p11b),
              "+v"(p12a), "+v"(p12b), "+v"(p13a), "+v"(p13b),
              "+v"(p14a), "+v"(p14b), "+v"(p15a), "+v"(p15b));
        __builtin_amdgcn_sched_barrier(0);
        __builtin_amdgcn_s_setprio(1);
        G2STEP(8, p8a, p8b)   G2STEP(9, p9a, p9b)
        G2STEP(10, p10a, p10b) G2STEP(11, p11a, p11b)
        G2STEP(12, p12a, p12b) G2STEP(13, p13a, p13b)
        G2STEP(14, p14a, p14b) G2STEP(15, p15a, p15b)
        __builtin_amdgcn_s_setprio(0);
#undef G2STEP
    }
}

// ---------------------------------------------------------------------------
extern "C" void kernel_launch(void* const* d_in, const int* in_sizes, int n_in,
                              void* d_out, int out_size, void* d_ws, size_t ws_size,
                              hipStream_t stream) {
    const float* x    = (const float*)d_in[0];
    const float* W1   = (const float*)d_in[1];
    const float* W2   = (const float*)d_in[2];
    const float* akey = (const float*)d_in[3];
    float* out = (float*)d_out;

    char* ws = (char*)d_ws;
    short* W1b     = (short*)ws;                       //   737,280 B
    short* W2b     = (short*)(ws + 737280);            //   983,040 B
    float* partial = (float*)(ws + 1720320);           // 3,145,728 B
    float* sims    = (float*)(ws + 4866048);           //    10,240 B
    int*   majorp  = (int*)(ws + 4876288);

    hipLaunchKernelGGL(kwa_fused, dim3(B_ * 4), dim3(256), 0, stream,
                       x, partial, W1, W2, W1b, W2b);
    hipLaunchKernelGGL(k1b_sims, dim3(B_), dim3(256), 0, stream, partial, akey, sims);
    hipLaunchKernelGGL(k2_select, dim3(1), dim3(256), 0, stream, sims, out, majorp);
    hipLaunchKernelGGL(k3_apply, dim3(NBLK), dim3(192), 0, stream, x, W1b, W2b, majorp, out);
}

// Round 28
// 121.430 us; speedup vs baseline: 1.1713x; 1.0130x over previous
//
#include <hip/hip_runtime.h>
#include <hip/hip_bf16.h>

// Problem constants
#define B_   256
#define L_   197
#define C_   768
#define H_   48
#define NA_  10
#define ROWS (B_ * L_)            // 50432
#define TR   16                   // K3 tile rows; 50432 = 16*3152 exactly
#define XP   776                  // xs pitch (bf16): 768+8
#define HP   72                   // hs pitch (bf16): 64+8
#define NBLK (ROWS / TR)          // 3152
#define OFF_SIM 38731776          // B*L*C
#define OFF_IDX 38731777

typedef __attribute__((ext_vector_type(8))) short short8;
typedef __attribute__((ext_vector_type(4))) short short4_t;
typedef __attribute__((ext_vector_type(4))) float f32x4;

static __device__ inline short f2bf(float f) {
    union { float f; unsigned u; } v; v.f = f;
    unsigned r = v.u + 0x7fffu + ((v.u >> 16) & 1u);   // round-to-nearest-even
    return (short)(r >> 16);
}
static __device__ inline short bfc(float f) {
    __hip_bfloat16 h = __float2bfloat16(f);
    union { __hip_bfloat16 h; short s; } u; u.h = h;
    return u.s;
}
static __device__ inline float bf2f(short s) {
    union { unsigned u; float f; } v;
    v.u = ((unsigned)(unsigned short)s) << 16;
    return v.f;
}

#define GLW(dst, p, OFF) asm volatile("global_load_dwordx4 %0, %1, off offset:" OFF \
    : "=v"(dst) : "v"(p))

// ---------------------------------------------------------------------------
// KWA: merged k1a + kw_convert. grid = B*4 blocks of 256 threads.
// ---------------------------------------------------------------------------
__global__ void kwa_fused(const float* __restrict__ x, float* __restrict__ partial,
                          const float* __restrict__ W1, const float* __restrict__ W2,
                          short* __restrict__ W1b, short* __restrict__ W2b) {
    int gid = blockIdx.x * 256 + threadIdx.x;  // 0..262143
    for (int i = gid; i < NA_ * H_ * C_; i += B_ * 4 * 256)   // 368640
        W1b[i] = f2bf(W1[i]);
    for (int i = gid; i < NA_ * C_ * 64; i += B_ * 4 * 256) { // 491520
        int k  = i & 63;
        int nc = i >> 6;                       // a*768 + c
        W2b[i] = (k < H_) ? f2bf(W2[nc * H_ + k]) : (short)0;
    }
    int t = threadIdx.x;
    if (t < 192) {
        int b = blockIdx.x >> 2, seg = blockIdx.x & 3;
        int l0 = seg * 50, l1 = l0 + 50; if (l1 > L_) l1 = L_;
        const float* xb = x + (size_t)b * L_ * C_ + t * 4;
        float4 s = {0.f, 0.f, 0.f, 0.f};
        #pragma unroll 5
        for (int l = l0; l < l1; ++l) {
            float4 v = *(const float4*)(xb + (size_t)l * C_);
            s.x += v.x; s.y += v.y; s.z += v.z; s.w += v.w;
        }
        *(float4*)(partial + ((size_t)b * 4 + seg) * C_ + t * 4) = s;
    }
}

// ---------------------------------------------------------------------------
// K1b: per-b mean -> sims[b][k]
// ---------------------------------------------------------------------------
__global__ void k1b_sims(const float* __restrict__ partial, const float* __restrict__ akey,
                         float* __restrict__ sims) {
    __shared__ float red[21][256];
    int b = blockIdx.x, t = threadIdx.x;
    const float* p = partial + (size_t)b * 4 * C_;
    float m[3];
    #pragma unroll
    for (int j = 0; j < 3; ++j) {
        int c = t + j * 256;
        m[j] = (p[c] + p[C_ + c] + p[2 * C_ + c] + p[3 * C_ + c]) * (1.f / (float)L_);
    }
    red[0][t] = m[0] * m[0] + m[1] * m[1] + m[2] * m[2];
    #pragma unroll
    for (int k = 0; k < NA_; ++k) {
        float kd = 0.f, kq = 0.f;
        #pragma unroll
        for (int j = 0; j < 3; ++j) {
            float kv = akey[k * C_ + t + j * 256];
            kd += m[j] * kv; kq += kv * kv;
        }
        red[1 + k][t] = kd; red[11 + k][t] = kq;
    }
    __syncthreads();
    for (int s = 128; s > 0; s >>= 1) {
        if (t < s) {
            #pragma unroll
            for (int q = 0; q < 21; ++q) red[q][t] += red[q][t + s];
        }
        __syncthreads();
    }
    if (t < NA_) {
        float msq = red[0][0];
        sims[b * NA_ + t] = red[1 + t][0] * rsqrtf(fmaxf(red[11 + t][0], 1e-12f))
                                          * rsqrtf(fmaxf(msq, 1e-12f));
    }
}

// ---------------------------------------------------------------------------
// K2: single block. argmax + majority vote + reduce_sim + idx
// ---------------------------------------------------------------------------
__global__ void k2_select(const float* __restrict__ sims, float* __restrict__ out,
                          int* __restrict__ majorp) {
    __shared__ int counts[NA_];
    __shared__ int majorS;
    __shared__ float rs[256];
    int t = threadIdx.x;                       // = b
    float s[NA_];
    #pragma unroll
    for (int k = 0; k < NA_; ++k) s[k] = sims[t * NA_ + k];
    int best = 0; float bv = s[0];
    #pragma unroll
    for (int k = 1; k < NA_; ++k) { if (s[k] > bv) { bv = s[k]; best = k; } }
    if (t < NA_) counts[t] = 0;
    __syncthreads();
    atomicAdd(&counts[best], 1);
    __syncthreads();
    if (t == 0) {
        int mj = 0, mc = counts[0];
        #pragma unroll
        for (int k = 1; k < NA_; ++k) { if (counts[k] > mc) { mc = counts[k]; mj = k; } }
        majorS = mj; *majorp = mj;
    }
    __syncthreads();
    int mj = majorS;
    rs[t] = s[mj];
    __syncthreads();
    for (int st = 128; st > 0; st >>= 1) { if (t < st) rs[t] += rs[t + st]; __syncthreads(); }
    if (t == 0) out[OFF_SIM] = rs[0] * (1.f / (float)B_);
    out[OFF_IDX + t] = (float)mj;
}

// ---------------------------------------------------------------------------
// K3: fused adapter apply with EARLY ISSUE of W bursts.
// grid = 3152 blocks x 192 threads (3 waves). LDS 27.1KB.
// (a) W1 first half issued BEFORE x-stage: its L2 latency hides under the x
//     HBM loads (queue: 12 W1 + 16 x; vmcnt(8) = W1 + 8 x rows done).
// (b) W1 second half issued after barrier, consumed after first 12 MFMAs.
// (c) All 32 W2 frags issued BEFORE the hs barrier (R20-k3b proven pattern):
//     latency overlaps barrier convergence instead of stalling after it.
// ---------------------------------------------------------------------------
__launch_bounds__(192, 2)
__global__ void k3_apply(const float* __restrict__ x, const short* __restrict__ W1b,
                         const short* __restrict__ W2b, const int* __restrict__ majorp,
                         float* __restrict__ out) {
    __shared__ short xs[TR * XP];              // 24,832 B
    __shared__ short hs[TR * HP];              //  2,304 B
    const int major = *majorp;

    int t = threadIdx.x;                       // 0..191
    int w = t >> 6, l = t & 63;
    int rbase = blockIdx.x * TR;
    int lo16 = l & 15;
    int g = l >> 4;                            // 0..3
    int klane = g * 8;

    const short* w1p = W1b + major * (H_ * C_) + (size_t)(w * 16 + lo16) * C_ + klane;
    short8 q0, q1, q2, q3, q4, q5, q6, q7, q8, q9, q10, q11;
    short8 q12, q13, q14, q15, q16, q17, q18, q19, q20, q21, q22, q23;

    // ---- 0) EARLY: issue W1 first half (independent of LDS) ----
    GLW(q0,  w1p, "0");    GLW(q1,  w1p, "64");   GLW(q2,  w1p, "128");
    GLW(q3,  w1p, "192");  GLW(q4,  w1p, "256");  GLW(q5,  w1p, "320");
    GLW(q6,  w1p, "384");  GLW(q7,  w1p, "448");  GLW(q8,  w1p, "512");
    GLW(q9,  w1p, "576");  GLW(q10, w1p, "640");  GLW(q11, w1p, "704");

    // ---- 1) stage x tile f32 -> bf16 LDS, forced-asm burst ----
    {
        const float* xsrc = x + (size_t)rbase * C_ + t * 4;
        const float* b0 = xsrc;                // rows 0,1
        const float* b1 = xsrc + 2 * C_;
        const float* b2 = xsrc + 4 * C_;
        const float* b3 = xsrc + 6 * C_;
        const float* b4 = xsrc + 8 * C_;
        const float* b5 = xsrc + 10 * C_;
        const float* b6 = xsrc + 12 * C_;
        const float* b7 = xsrc + 14 * C_;
        f32x4 v0, v1, v2, v3, v4, v5, v6, v7, v8, v9, v10, v11, v12, v13, v14, v15;
        GLW(v0,  b0, "0"); GLW(v1,  b0, "3072");
        GLW(v2,  b1, "0"); GLW(v3,  b1, "3072");
        GLW(v4,  b2, "0"); GLW(v5,  b2, "3072");
        GLW(v6,  b3, "0"); GLW(v7,  b3, "3072");
        GLW(v8,  b4, "0"); GLW(v9,  b4, "3072");
        GLW(v10, b5, "0"); GLW(v11, b5, "3072");
        GLW(v12, b6, "0"); GLW(v13, b6, "3072");
        GLW(v14, b7, "0"); GLW(v15, b7, "3072");

#define STROW(ROW, V) { \
        short4_t sb; \
        sb[0] = bfc((V)[0]); sb[1] = bfc((V)[1]); \
        sb[2] = bfc((V)[2]); sb[3] = bfc((V)[3]); \
        *(short4_t*)&xs[(ROW) * XP + t * 4] = sb; }

        // queue: 12 W1 + 16 x = 28; vmcnt(8) -> 12 W1 + v0..v7 complete
        asm volatile("s_waitcnt vmcnt(8)"
            : "+v"(v0), "+v"(v1), "+v"(v2), "+v"(v3),
              "+v"(v4), "+v"(v5), "+v"(v6), "+v"(v7),
              "+v"(q0), "+v"(q1), "+v"(q2), "+v"(q3), "+v"(q4), "+v"(q5),
              "+v"(q6), "+v"(q7), "+v"(q8), "+v"(q9), "+v"(q10), "+v"(q11));
        __builtin_amdgcn_sched_barrier(0);
        STROW(0, v0) STROW(1, v1) STROW(2, v2) STROW(3, v3)
        STROW(4, v4) STROW(5, v5) STROW(6, v6) STROW(7, v7)
        asm volatile("s_waitcnt vmcnt(0)"
            : "+v"(v8), "+v"(v9), "+v"(v10), "+v"(v11),
              "+v"(v12), "+v"(v13), "+v"(v14), "+v"(v15));
        __builtin_amdgcn_sched_barrier(0);
        STROW(8, v8)   STROW(9, v9)   STROW(10, v10) STROW(11, v11)
        STROW(12, v12) STROW(13, v13) STROW(14, v14) STROW(15, v15)
#undef STROW
    }
    __syncthreads();

    // ---- 2) GEMM1: wave w computes n-tile w of h = relu(x @ W1^T) ----
    {
        f32x4 acc = {0, 0, 0, 0};

#define G1STEP(KK, Q) { \
        short8 xa = *(const short8*)&xs[lo16 * XP + (KK) * 32 + klane]; \
        acc = __builtin_amdgcn_mfma_f32_16x16x32_bf16(xa, Q, acc, 0, 0, 0); }

        // issue W1 second half; its latency hides under the first 12 MFMAs
        GLW(q12, w1p, "768");  GLW(q13, w1p, "832");  GLW(q14, w1p, "896");
        GLW(q15, w1p, "960");  GLW(q16, w1p, "1024"); GLW(q17, w1p, "1088");
        GLW(q18, w1p, "1152"); GLW(q19, w1p, "1216"); GLW(q20, w1p, "1280");
        GLW(q21, w1p, "1344"); GLW(q22, w1p, "1408"); GLW(q23, w1p, "1472");

        __builtin_amdgcn_s_setprio(1);
        G1STEP(0, q0)  G1STEP(1, q1)  G1STEP(2, q2)  G1STEP(3, q3)
        G1STEP(4, q4)  G1STEP(5, q5)  G1STEP(6, q6)  G1STEP(7, q7)
        G1STEP(8, q8)  G1STEP(9, q9)  G1STEP(10, q10) G1STEP(11, q11)
        __builtin_amdgcn_s_setprio(0);
        asm volatile("s_waitcnt vmcnt(0)"
            : "+v"(q12), "+v"(q13), "+v"(q14), "+v"(q15), "+v"(q16), "+v"(q17),
              "+v"(q18), "+v"(q19), "+v"(q20), "+v"(q21), "+v"(q22), "+v"(q23));
        __builtin_amdgcn_sched_barrier(0);
        __builtin_amdgcn_s_setprio(1);
        G1STEP(12, q12) G1STEP(13, q13) G1STEP(14, q14) G1STEP(15, q15)
        G1STEP(16, q16) G1STEP(17, q17) G1STEP(18, q18) G1STEP(19, q19)
        G1STEP(20, q20) G1STEP(21, q21) G1STEP(22, q22) G1STEP(23, q23)
        __builtin_amdgcn_s_setprio(0);
#undef G1STEP

        // h -> hs (D: col n=lo16 (W1 row), row m=g*4+q (x row))
        #pragma unroll
        for (int q = 0; q < 4; ++q)
            hs[(g * 4 + q) * HP + w * 16 + lo16] = bfc(fmaxf(acc[q], 0.f));
        // K-pad zero [48,64): wave 0 covers 16 rows x 16 cols
        if (w == 0) {
            short4_t z = {0, 0, 0, 0};
            *(short4_t*)&hs[lo16 * HP + 48 + g * 4] = z;
        }
    }

    // ---- 3) GEMM2: EARLY W2 issue (independent of hs), then barrier ----
    {
        const short* ba = W2b + (size_t)major * (C_ * 64)
                              + (size_t)(w * 16) * 1024 + lo16 * 64 + klane;
        const short* b1 = ba + 2048;
        const short* b2 = ba + 4096;
        const short* b3 = ba + 6144;
        const short* b4 = ba + 8192;
        const short* b5 = ba + 10240;
        const short* b6 = ba + 12288;
        const short* b7 = ba + 14336;
        short8 p0a, p0b, p1a, p1b, p2a, p2b, p3a, p3b;
        short8 p4a, p4b, p5a, p5b, p6a, p6b, p7a, p7b;
        short8 p8a, p8b, p9a, p9b, p10a, p10b, p11a, p11b;
        short8 p12a, p12b, p13a, p13b, p14a, p14b, p15a, p15b;

        GLW(p0a,  ba, "0");    GLW(p0b,  ba, "64");
        GLW(p1a,  ba, "2048"); GLW(p1b,  ba, "2112");
        GLW(p2a,  b1, "0");    GLW(p2b,  b1, "64");
        GLW(p3a,  b1, "2048"); GLW(p3b,  b1, "2112");
        GLW(p4a,  b2, "0");    GLW(p4b,  b2, "64");
        GLW(p5a,  b2, "2048"); GLW(p5b,  b2, "2112");
        GLW(p6a,  b3, "0");    GLW(p6b,  b3, "64");
        GLW(p7a,  b3, "2048"); GLW(p7b,  b3, "2112");
        GLW(p8a,  b4, "0");    GLW(p8b,  b4, "64");
        GLW(p9a,  b4, "2048"); GLW(p9b,  b4, "2112");
        GLW(p10a, b5, "0");    GLW(p10b, b5, "64");
        GLW(p11a, b5, "2048"); GLW(p11b, b5, "2112");
        GLW(p12a, b6, "0");    GLW(p12b, b6, "64");
        GLW(p13a, b6, "2048"); GLW(p13b, b6, "2112");
        GLW(p14a, b7, "0");    GLW(p14b, b7, "64");
        GLW(p15a, b7, "2048"); GLW(p15b, b7, "2112");

        __syncthreads();                       // hs visible; W2 latency overlapped

        short8 hA = *(const short8*)&hs[lo16 * HP + klane];
        short8 hB = *(const short8*)&hs[lo16 * HP + 32 + klane];
        float* outr = out + (size_t)(rbase + lo16) * C_ + w * 256 + g * 4;

#define G2STEP(JJ, P0, P1) { \
        f32x4 acc = {0, 0, 0, 0}; \
        acc = __builtin_amdgcn_mfma_f32_16x16x32_bf16(P0, hA, acc, 0, 0, 0); \
        acc = __builtin_amdgcn_mfma_f32_16x16x32_bf16(P1, hB, acc, 0, 0, 0); \
        short4_t xbv = *(const short4_t*)&xs[lo16 * XP + (w * 16 + (JJ)) * 16 + g * 4]; \
        f32x4 ov; \
        ov[0] = bf2f(xbv[0]) + fmaxf(acc[0], 0.f); \
        ov[1] = bf2f(xbv[1]) + fmaxf(acc[1], 0.f); \
        ov[2] = bf2f(xbv[2]) + fmaxf(acc[2], 0.f); \
        ov[3] = bf2f(xbv[3]) + fmaxf(acc[3], 0.f); \
        *(f32x4*)(outr + (JJ) * 16) = ov; }

        asm volatile("s_waitcnt vmcnt(16)"
            : "+v"(p0a), "+v"(p0b), "+v"(p1a), "+v"(p1b),
              "+v"(p2a), "+v"(p2b), "+v"(p3a), "+v"(p3b),
              "+v"(p4a), "+v"(p4b), "+v"(p5a), "+v"(p5b),
              "+v"(p6a), "+v"(p6b), "+v"(p7a), "+v"(p7b));
        __builtin_amdgcn_sched_barrier(0);
        __builtin_amdgcn_s_setprio(1);
        G2STEP(0, p0a, p0b)   G2STEP(1, p1a, p1b)
        G2STEP(2, p2a, p2b)   G2STEP(3, p3a, p3b)
        G2STEP(4, p4a, p4b)   G2STEP(5, p5a, p5b)
        G2STEP(6, p6a, p6b)   G2STEP(7, p7a, p7b)
        __builtin_amdgcn_s_setprio(0);
        asm volatile("s_waitcnt vmcnt(0)"
            : "+v"(p8a), "+v"(p8b), "+v"(p9a), "+v"(p9b),
              "+v"(p10a), "+v"(p10b), "+v"(p11a), "+v"(p11b),
              "+v"(p12a), "+v"(p12b), "+v"(p13a), "+v"(p13b),
              "+v"(p14a), "+v"(p14b), "+v"(p15a), "+v"(p15b));
        __builtin_amdgcn_sched_barrier(0);
        __builtin_amdgcn_s_setprio(1);
        G2STEP(8, p8a, p8b)   G2STEP(9, p9a, p9b)
        G2STEP(10, p10a, p10b) G2STEP(11, p11a, p11b)
        G2STEP(12, p12a, p12b) G2STEP(13, p13a, p13b)
        G2STEP(14, p14a, p14b) G2STEP(15, p15a, p15b)
        __builtin_amdgcn_s_setprio(0);
#undef G2STEP
    }
}

// ---------------------------------------------------------------------------
extern "C" void kernel_launch(void* const* d_in, const int* in_sizes, int n_in,
                              void* d_out, int out_size, void* d_ws, size_t ws_size,
                              hipStream_t stream) {
    const float* x    = (const float*)d_in[0];
    const float* W1   = (const float*)d_in[1];
    const float* W2   = (const float*)d_in[2];
    const float* akey = (const float*)d_in[3];
    float* out = (float*)d_out;

    char* ws = (char*)d_ws;
    short* W1b     = (short*)ws;                       //   737,280 B
    short* W2b     = (short*)(ws + 737280);            //   983,040 B
    float* partial = (float*)(ws + 1720320);           // 3,145,728 B
    float* sims    = (float*)(ws + 4866048);           //    10,240 B
    int*   majorp  = (int*)(ws + 4876288);

    hipLaunchKernelGGL(kwa_fused, dim3(B_ * 4), dim3(256), 0, stream,
                       x, partial, W1, W2, W1b, W2b);
    hipLaunchKernelGGL(k1b_sims, dim3(B_), dim3(256), 0, stream, partial, akey, sims);
    hipLaunchKernelGGL(k2_select, dim3(1), dim3(256), 0, stream, sims, out, majorp);
    hipLaunchKernelGGL(k3_apply, dim3(NBLK), dim3(192), 0, stream, x, W1b, W2b, majorp, out);
}